// Round 6
// baseline (23.450 us; speedup 1.0000x reference)
//
#include <hip/hip_runtime.h>
#include <math.h>

// Problem constants (fixed by setup_inputs: B=64, HW=6400 (80x80), C=85, T=50)
constexpr int B_  = 64;
constexpr int HW_ = 6400;
constexpr int C_  = 85;
constexpr int T_  = 50;
constexpr int H_  = 80;
constexpr int W_  = 80;
constexpr float LC    = 5.0f;              // LAMBDA_COORD
constexpr float LN    = 0.5f;              // LAMBDA_NOOBJ
constexpr float INV_N = 1.0f / (B_ * T_);  // 1/num_objects

// 6400 waves: wave gw owns 64 conf cells of image gw/100; if gw%100 < 50 it
// also owns object (gw/100)*50 + gw%100 (same image!). 4 waves/block -> 1600
// blocks = 409,600 threads = exactly full residency (2048/CU x 200 CUs used).
constexpr int GRID_A = 1600;
constexpr int NPART  = GRID_A + B_ * T_;   // 1600 scan + 3200 obj = 4800 floats

__device__ __forceinline__ float softplus_f(float x) {
    return fmaxf(x, 0.0f) + log1pf(expf(-fabsf(x)));   // stable log(1+e^x)
}

__global__ __launch_bounds__(256) void main_kernel(
    const float* __restrict__ pred, const float* __restrict__ tbox,
    const int* __restrict__ tcls, float* __restrict__ partial)
{
    int lane = threadIdx.x & 63;
    int wid  = threadIdx.x >> 6;
    int gw   = blockIdx.x * 4 + wid;
    int bi   = gw / 100;           // image (block-uniform: 25 blocks/image)
    int wi   = gw % 100;           // wave slot within image
    __shared__ float ss[4];

    // ---- issue the scan load early (1 conf value per lane) ----
    int cell = wi * 64 + lane;
    float conf = pred[((size_t)bi * HW_ + cell) * C_ + 4];

    // ---- duplicate mask for image bi (lane l holds grid idx of object l) ----
    int gio;
    if (lane < T_) {
        const float4 to = ((const float4*)tbox)[bi * T_ + lane];
        gio = (int)(floorf(to.y * (float)H_) * (float)W_ +
                    floorf(to.x * (float)W_));
    } else {
        gio = 0x40000000 + lane;   // unique sentinel
    }
    bool dup = false;
    #pragma unroll
    for (int k = 0; k < T_ - 1; ++k) {
        int gk = __shfl(gio, k, 64);
        dup = dup || ((lane > k) && (gio == gk));
    }
    unsigned long long dm = __ballot(dup);
    int n_unique = T_ - __popcll(dm);
    float nn = fmaxf((float)(HW_ - n_unique), 1.0f);   // no-object cell count

    // ---- scan: softplus + wave reduce ----
    float s = softplus_f(conf);
    #pragma unroll
    for (int off = 32; off; off >>= 1) s += __shfl_xor(s, off, 64);
    if (lane == 0) ss[wid] = s;

    // ---- object path (waves with wi < 50) ----
    if (wi < T_) {
        int obj = bi * T_ + wi;
        int gi  = __shfl(gio, wi, 64);              // object's grid cell
        bool canonical = !((dm >> wi) & 1ULL);

        const float4 tb = ((const float4*)tbox)[obj];   // cx, cy, w, h
        float gxf = floorf(tb.x * (float)W_);
        float gyf = floorf(tb.y * (float)H_);

        const float* g = pred + ((size_t)bi * HW_ + gi) * C_;
        int cls = tcls[obj];

        int   c2 = lane + 64;
        float v1 = g[lane];
        float v2 = (c2 < C_) ? g[c2] : 0.0f;

        // logsumexp over class channels 5..84
        float m = -1e30f;
        if (lane >= 5) m = v1;
        if (c2 < C_)   m = fmaxf(m, v2);
        #pragma unroll
        for (int off = 32; off; off >>= 1) m = fmaxf(m, __shfl_xor(m, off, 64));
        float e = 0.0f;
        if (lane >= 5) e += expf(v1 - m);
        if (c2 < C_)   e += expf(v2 - m);
        #pragma unroll
        for (int off = 32; off; off >>= 1) e += __shfl_xor(e, off, 64);
        float lse = m + logf(e);

        float contrib = 0.0f;
        if (lane == 0) {          // xy: mean over 2 comps -> 0.5 each, * LC
            float d = 1.0f / (1.0f + expf(-v1)) - (tb.x * (float)W_ - gxf);
            contrib = LC * 0.5f * d * d;
        } else if (lane == 1) {
            float d = 1.0f / (1.0f + expf(-v1)) - (tb.y * (float)H_ - gyf);
            contrib = LC * 0.5f * d * d;
        } else if (lane == 2) {
            float d = v1 - logf(tb.z * (float)W_ + 1e-16f);
            contrib = LC * 0.5f * d * d;
        } else if (lane == 3) {
            float d = v1 - logf(tb.w * (float)H_ + 1e-16f);
            contrib = LC * 0.5f * d * d;
        } else if (lane == 4) {
            contrib = softplus_f(-v1);                   // objectness BCE
            if (canonical) contrib -= LN * softplus_f(v1) / nn;  // -masked noobj
        }
        if (lane == 5 + cls) contrib += lse - v1;        // class CE
        if (c2   == 5 + cls) contrib += lse - v2;

        #pragma unroll
        for (int off = 32; off; off >>= 1) contrib += __shfl_xor(contrib, off, 64);
        if (lane == 0) partial[GRID_A + obj] = contrib;
    }

    __syncthreads();
    if (threadIdx.x == 0)   // wave 0's nn is for image blockIdx/25 == bi ✓
        partial[blockIdx.x] = LN * (ss[0] + ss[1] + ss[2] + ss[3]) / nn;
}

// Kernel B: one block sums the 4800 partials (1200 float4, coalesced) -> out.
__global__ __launch_bounds__(256) void reduce_kernel(
    const float* __restrict__ partial, float* __restrict__ out)
{
    const float4* p4 = (const float4*)partial;   // 4800/4 = 1200
    float s = 0.0f;
    for (int i = threadIdx.x; i < NPART / 4; i += 256) {
        float4 v = p4[i];
        s += (v.x + v.y) + (v.z + v.w);
    }
    #pragma unroll
    for (int off = 32; off; off >>= 1) s += __shfl_xor(s, off, 64);

    __shared__ float ss[4];
    int wid = threadIdx.x >> 6;
    if ((threadIdx.x & 63) == 0) ss[wid] = s;
    __syncthreads();
    if (threadIdx.x == 0)
        out[0] = (ss[0] + ss[1] + ss[2] + ss[3]) * INV_N;
}

extern "C" void kernel_launch(void* const* d_in, const int* in_sizes, int n_in,
                              void* d_out, int out_size, void* d_ws, size_t ws_size,
                              hipStream_t stream) {
    const float* pred = (const float*)d_in[0];
    const float* tbox = (const float*)d_in[1];
    const int*   tcls = (const int*)d_in[2];
    float* out = (float*)d_out;
    float* partial = (float*)d_ws;   // [4800], fully written each call before read

    main_kernel  <<<GRID_A, 256, 0, stream>>>(pred, tbox, tcls, partial);
    reduce_kernel<<<1,      256, 0, stream>>>(partial, out);
}

// Round 7
// 20.290 us; speedup vs baseline: 1.1558x; 1.1558x over previous
//
#include <hip/hip_runtime.h>
#include <math.h>

// Problem constants (fixed by setup_inputs: B=64, HW=6400 (80x80), C=85, T=50)
constexpr int B_  = 64;
constexpr int HW_ = 6400;
constexpr int C_  = 85;
constexpr int T_  = 50;
constexpr int H_  = 80;
constexpr int W_  = 80;
constexpr float LC    = 5.0f;              // LAMBDA_COORD
constexpr float LN    = 0.5f;              // LAMBDA_NOOBJ
constexpr float INV_N = 1.0f / (B_ * T_);  // 1/num_objects

constexpr int OBJ_BLOCKS  = (B_ * T_) / 4;    // 800 blocks, 4 obj-waves each
constexpr int SUBN        = 16;               // scan blocks per image
constexpr int SCAN_BLOCKS = B_ * SUBN;        // 1024
constexpr int CHUNK       = HW_ / SUBN;       // 400 cells per scan block
constexpr int GRID_A      = OBJ_BLOCKS + SCAN_BLOCKS;  // 1824 = 7296 waves <= 8192
constexpr int NPART       = SCAN_BLOCKS + B_ * T_;     // 1024 + 3200 = 4224

__device__ __forceinline__ float softplus_f(float x) {
    return fmaxf(x, 0.0f) + log1pf(expf(-fabsf(x)));   // stable log(1+e^x)
}

// Wave-wide: lane l (<50) holds grid index of object l of image b.
// Returns (via refs) the dup mask and this image's no-object cell count.
__device__ __forceinline__ void image_dup_info(
    const float* __restrict__ tbox, int b, int lane,
    unsigned long long& dm, float& nn, int& gio)
{
    if (lane < T_) {
        const float4 to = ((const float4*)tbox)[b * T_ + lane];
        gio = (int)(floorf(to.y * (float)H_) * (float)W_ +
                    floorf(to.x * (float)W_));
    } else {
        gio = 0x40000000 + lane;   // unique sentinel
    }
    bool dup = false;
    #pragma unroll
    for (int k = 0; k < T_ - 1; ++k) {
        int gk = __shfl(gio, k, 64);
        dup = dup || ((lane > k) && (gio == gk));
    }
    dm = __ballot(dup);
    int n_unique = T_ - __popcll(dm);
    nn = fmaxf((float)(HW_ - n_unique), 1.0f);
}

// Kernel A. Blocks [0,800): 4 object-waves each. Blocks [800,1824): conf scan,
// 400 cells each. All partials pre-scaled so the final result is a plain sum.
__global__ __launch_bounds__(256) void main_kernel(
    const float* __restrict__ pred, const float* __restrict__ tbox,
    const int* __restrict__ tcls, float* __restrict__ partial)
{
    int lane = threadIdx.x & 63;
    int wid  = threadIdx.x >> 6;

    if (blockIdx.x < OBJ_BLOCKS) {
        // ---- per-object wave ----
        int obj = blockIdx.x * 4 + wid;
        int b   = obj / T_;
        int myt = obj % T_;

        // own box -> cell; issue gather loads EARLY (overlap with shfl chain)
        const float4 tb = ((const float4*)tbox)[obj];   // cx, cy, w, h
        float gxf = floorf(tb.x * (float)W_);
        float gyf = floorf(tb.y * (float)H_);
        int gi = (int)(gyf * (float)W_ + gxf);

        const float* g = pred + ((size_t)b * HW_ + gi) * C_;
        int   c2 = lane + 64;
        float v1 = g[lane];
        float v2 = (c2 < C_) ? g[c2] : 0.0f;
        int cls = tcls[obj];

        unsigned long long dm; float nn; int gio;
        image_dup_info(tbox, b, lane, dm, nn, gio);
        bool canonical = !((dm >> myt) & 1ULL);

        // logsumexp over class channels 5..84
        float m = -1e30f;
        if (lane >= 5) m = v1;
        if (c2 < C_)   m = fmaxf(m, v2);
        #pragma unroll
        for (int off = 32; off; off >>= 1) m = fmaxf(m, __shfl_xor(m, off, 64));
        float e = 0.0f;
        if (lane >= 5) e += expf(v1 - m);
        if (c2 < C_)   e += expf(v2 - m);
        #pragma unroll
        for (int off = 32; off; off >>= 1) e += __shfl_xor(e, off, 64);
        float lse = m + logf(e);

        float contrib = 0.0f;
        if (lane == 0) {          // xy: mean over 2 comps -> 0.5 each, * LC
            float d = 1.0f / (1.0f + expf(-v1)) - (tb.x * (float)W_ - gxf);
            contrib = LC * 0.5f * d * d;
        } else if (lane == 1) {
            float d = 1.0f / (1.0f + expf(-v1)) - (tb.y * (float)H_ - gyf);
            contrib = LC * 0.5f * d * d;
        } else if (lane == 2) {
            float d = v1 - logf(tb.z * (float)W_ + 1e-16f);
            contrib = LC * 0.5f * d * d;
        } else if (lane == 3) {
            float d = v1 - logf(tb.w * (float)H_ + 1e-16f);
            contrib = LC * 0.5f * d * d;
        } else if (lane == 4) {
            contrib = softplus_f(-v1);                   // objectness BCE
            if (canonical) contrib -= LN * softplus_f(v1) / nn;  // -masked noobj
        }
        if (lane == 5 + cls) contrib += lse - v1;        // class CE
        if (c2   == 5 + cls) contrib += lse - v2;

        #pragma unroll
        for (int off = 32; off; off >>= 1) contrib += __shfl_xor(contrib, off, 64);
        if (lane == 0) partial[SCAN_BLOCKS + obj] = contrib;
    } else {
        // ---- conf softplus scan: 400 cells, loads issued first ----
        int c   = blockIdx.x - OBJ_BLOCKS;
        int b   = c >> 4;           // image
        int sub = c & 15;
        const float* p = pred + (size_t)b * HW_ * C_ + 4;   // conf channel

        int i1 = sub * CHUNK + (int)threadIdx.x;
        float conf1 = p[(size_t)i1 * C_];
        float conf2 = 0.0f;
        bool has2 = threadIdx.x < (CHUNK - 256);            // 144 threads
        if (has2) conf2 = p[(size_t)(i1 + 256) * C_];

        unsigned long long dm; float nn; int gio;
        image_dup_info(tbox, b, lane, dm, nn, gio);

        float s = softplus_f(conf1);
        if (has2) s += softplus_f(conf2);
        #pragma unroll
        for (int off = 32; off; off >>= 1) s += __shfl_xor(s, off, 64);

        __shared__ float ss[4];
        if (lane == 0) ss[wid] = s;
        __syncthreads();
        if (threadIdx.x == 0)
            partial[c] = LN * (ss[0] + ss[1] + ss[2] + ss[3]) / nn;
    }
}

// Kernel B: one block sums the 4224 partials (1056 float4, coalesced) -> out.
__global__ __launch_bounds__(256) void reduce_kernel(
    const float* __restrict__ partial, float* __restrict__ out)
{
    const float4* p4 = (const float4*)partial;   // 4224/4 = 1056
    float s = 0.0f;
    for (int i = threadIdx.x; i < NPART / 4; i += 256) {
        float4 v = p4[i];
        s += (v.x + v.y) + (v.z + v.w);
    }
    #pragma unroll
    for (int off = 32; off; off >>= 1) s += __shfl_xor(s, off, 64);

    __shared__ float ss[4];
    int wid = threadIdx.x >> 6;
    if ((threadIdx.x & 63) == 0) ss[wid] = s;
    __syncthreads();
    if (threadIdx.x == 0)
        out[0] = (ss[0] + ss[1] + ss[2] + ss[3]) * INV_N;
}

extern "C" void kernel_launch(void* const* d_in, const int* in_sizes, int n_in,
                              void* d_out, int out_size, void* d_ws, size_t ws_size,
                              hipStream_t stream) {
    const float* pred = (const float*)d_in[0];
    const float* tbox = (const float*)d_in[1];
    const int*   tcls = (const int*)d_in[2];
    float* out = (float*)d_out;
    float* partial = (float*)d_ws;   // [4224], fully written each call before read

    main_kernel  <<<GRID_A, 256, 0, stream>>>(pred, tbox, tcls, partial);
    reduce_kernel<<<1,      256, 0, stream>>>(partial, out);
}